// Round 2
// baseline (244.551 us; speedup 1.0000x reference)
//
#include <hip/hip_runtime.h>

// RNNAdder: out[row] = digits of (a[row] + b[row]) in base 10, MSB-first,
// with a leading final-carry column. a,b (B,2048) f32 digits 0..9;
// out (B,2049) int32.
//
// One WAVE per row (barrier-free), 4 rows per 256-thread block.
// Each lane owns 32 contiguous digits; carry propagation via
// generate/propagate monoid scan done entirely with __shfl_up (no LDS).

#define NDIG 2048
#define TPB 256
#define DPT 32           // digits per lane
#define RPB 4            // rows (waves) per block

__global__ __launch_bounds__(TPB) void rnn_adder_kernel(
    const float* __restrict__ A, const float* __restrict__ B,
    int* __restrict__ out) {
  const int wave = threadIdx.x >> 6;
  const int lane = threadIdx.x & 63;
  const int row = blockIdx.x * RPB + wave;
  // lane 0 owns the rightmost (least significant) chunk; carry flows 0 -> 63.
  const int base = NDIG - (lane + 1) * DPT;

  const float4* A4 = reinterpret_cast<const float4*>(A + (size_t)row * NDIG + base);
  const float4* B4 = reinterpret_cast<const float4*>(B + (size_t)row * NDIG + base);

  // Issue all 16 loads up front for maximum memory-level parallelism.
  float4 av[DPT / 4], bv[DPT / 4];
#pragma unroll
  for (int q = 0; q < DPT / 4; ++q) av[q] = A4[q];
#pragma unroll
  for (int q = 0; q < DPT / 4; ++q) bv[q] = B4[q];

  int s[DPT];
#pragma unroll
  for (int q = 0; q < DPT / 4; ++q) {
    s[4 * q + 0] = (int)(av[q].x + bv[q].x);
    s[4 * q + 1] = (int)(av[q].y + bv[q].y);
    s[4 * q + 2] = (int)(av[q].z + bv[q].z);
    s[4 * q + 3] = (int)(av[q].w + bv[q].w);
  }

  // Carry-transfer function of this 32-digit chunk, evaluated at cin=0 and 1.
  // s+c in 0..19; s+c>=10  <=>  bit5 of (s+c+22). v_add3 + v_bfe per step.
  int c0 = 0, c1 = 1;
#pragma unroll
  for (int k = DPT - 1; k >= 0; --k) {   // s[DPT-1] is chunk LSB
    c0 = ((s[k] + c0 + 22) >> 5) & 1;
    c1 = ((s[k] + c1 + 22) >> 5) & 1;
  }

  // Pack f: bit0 = f(0), bit1 = f(1). Identity = 0b10.
  int cur = c0 | (c1 << 1);
  // Inclusive Kogge-Stone composition scan across the wave, branch-free.
#pragma unroll
  for (int off = 1; off < 64; off <<= 1) {
    int prev = __shfl_up(cur, off, 64);
    prev = (lane >= off) ? prev : 2;  // identity below
    // cur = cur o prev (prev applied first)
    cur = ((cur >> (prev & 1)) & 1) | (((cur >> ((prev >> 1) & 1)) & 1) << 1);
  }

  // Incoming carry = exclusive scan evaluated at 0.
  int pr = __shfl_up(cur, 1, 64);
  int cin = (lane == 0) ? 0 : (pr & 1);

  // Finalize digits (chunk LSB first), reuse s[] for output digits.
  int c = cin;
#pragma unroll
  for (int k = DPT - 1; k >= 0; --k) {
    int v = s[k] + c;
    c = ((v + 22) >> 5) & 1;
    s[k] = v - 10 * c;
  }

  int* orow = out + (size_t)row * (NDIG + 1);
#pragma unroll
  for (int k = 0; k < DPT; ++k)
    __builtin_nontemporal_store(s[k], orow + 1 + base + k);
  if (lane == 63) __builtin_nontemporal_store(c, orow);  // final carry (MSB chunk)
}

extern "C" void kernel_launch(void* const* d_in, const int* in_sizes, int n_in,
                              void* d_out, int out_size, void* d_ws, size_t ws_size,
                              hipStream_t stream) {
  const float* A = (const float*)d_in[0];
  const float* B = (const float*)d_in[1];
  int* out = (int*)d_out;
  const int rows = in_sizes[0] / NDIG;
  rnn_adder_kernel<<<rows / RPB, TPB, 0, stream>>>(A, B, out);
}

// Round 3
// 75.239 us; speedup vs baseline: 3.2503x; 3.2503x over previous
//
#include <hip/hip_runtime.h>

// RNNAdder: out[row] = digits of (a[row] + b[row]) in base 10, MSB-first,
// with a leading final-carry column. a,b (B,2048) f32 digits 0..9;
// out (B,2049) int32.
//
// Block-per-row, 256 threads, 8 digits/thread (round-1 memory pattern:
// both FETCH and WRITE profiled at ideal bytes). Carry scan:
//   wave-local __shfl_up composition scan (no barriers)
//   + single LDS exchange of 4 wave aggregates (1 barrier).

#define NDIG 2048
#define TPB 256
#define DPT 8
#define NW (TPB / 64)

__global__ __launch_bounds__(TPB) void rnn_adder_kernel(
    const float* __restrict__ A, const float* __restrict__ B,
    int* __restrict__ out) {
  const int t = threadIdx.x;
  const int lane = t & 63;
  const int wave = t >> 6;
  const int row = blockIdx.x;
  // t=0 owns the rightmost (least significant) chunk; carry flows t=0 -> 255.
  const int base = NDIG - (t + 1) * DPT;

  const float4* A4 = reinterpret_cast<const float4*>(A + (size_t)row * NDIG + base);
  const float4* B4 = reinterpret_cast<const float4*>(B + (size_t)row * NDIG + base);
  float4 a0 = A4[0], a1 = A4[1];
  float4 b0 = B4[0], b1 = B4[1];

  int s[DPT];
  s[0] = (int)(a0.x + b0.x);
  s[1] = (int)(a0.y + b0.y);
  s[2] = (int)(a0.z + b0.z);
  s[3] = (int)(a0.w + b0.w);
  s[4] = (int)(a1.x + b1.x);
  s[5] = (int)(a1.y + b1.y);
  s[6] = (int)(a1.z + b1.z);
  s[7] = (int)(a1.w + b1.w);

  // Chunk carry-transfer evaluated at cin=0,1. s+c in 0..19; (s+c)>=10 <=>
  // bit5 of (s+c+22) -> v_add3 + v_bfe, branch-free.
  int c0 = 0, c1 = 1;
#pragma unroll
  for (int k = DPT - 1; k >= 0; --k) {  // s[DPT-1] is chunk LSB
    c0 = ((s[k] + c0 + 22) >> 5) & 1;
    c1 = ((s[k] + c1 + 22) >> 5) & 1;
  }

  // Packed transfer f: bit0=f(0), bit1=f(1). Identity = 0b10.
  int cur = c0 | (c1 << 1);
  // Inclusive wave-local Kogge-Stone composition scan, barrier-free.
#pragma unroll
  for (int off = 1; off < 64; off <<= 1) {
    int prev = __shfl_up(cur, off, 64);
    prev = (lane >= off) ? prev : 2;
    cur = ((cur >> (prev & 1)) & 1) | (((cur >> ((prev >> 1) & 1)) & 1) << 1);
  }

  // Cross-wave: exchange per-wave aggregate transfers via LDS (1 barrier).
  __shared__ int wagg[NW];
  if (lane == 63) wagg[wave] = cur;
  __syncthreads();

  // Carry into this wave = F_{wave-1} o ... o F_0 applied to 0.
  int wc = 0;
  for (int w = 0; w < wave; ++w) wc = (wagg[w] >> wc) & 1;  // wave-uniform

  // Carry into this thread = (composed transfer of lanes below) applied to wc.
  int pr = __shfl_up(cur, 1, 64);
  int cin = (lane == 0) ? wc : ((pr >> wc) & 1);

  // Finalize digits (chunk LSB first); reuse s[] as output digits.
  int c = cin;
#pragma unroll
  for (int k = DPT - 1; k >= 0; --k) {
    int v = s[k] + c;
    c = ((v + 22) >> 5) & 1;
    s[k] = v - 10 * c;
  }

  int* orow = out + (size_t)row * (NDIG + 1);
#pragma unroll
  for (int k = 0; k < DPT; ++k) orow[1 + base + k] = s[k];
  if (t == TPB - 1) orow[0] = c;  // final carry (MSB chunk)
}

extern "C" void kernel_launch(void* const* d_in, const int* in_sizes, int n_in,
                              void* d_out, int out_size, void* d_ws, size_t ws_size,
                              hipStream_t stream) {
  const float* A = (const float*)d_in[0];
  const float* B = (const float*)d_in[1];
  int* out = (int*)d_out;
  const int rows = in_sizes[0] / NDIG;
  rnn_adder_kernel<<<rows, TPB, 0, stream>>>(A, B, out);
}